// Round 4
// baseline (366.270 us; speedup 1.0000x reference)
//
#include <hip/hip_runtime.h>

typedef __attribute__((ext_vector_type(8))) short bf16x8;
typedef __attribute__((ext_vector_type(8))) unsigned short u16x8;
typedef __attribute__((ext_vector_type(4))) float f32x4;

__device__ __forceinline__ unsigned short f2bf(float f) {
    unsigned int u = __float_as_uint(f);
    u += 0x7fffu + ((u >> 16) & 1u);   // RNE
    return (unsigned short)(u >> 16);
}

// ---------------- Kernel 1: row-normalize fp32 -> bf16 ----------------
__global__ __launch_bounds__(256) void normalize_rows(
    const float* __restrict__ X, unsigned short* __restrict__ Y) {
    const int wave = threadIdx.x >> 6;
    const int lane = threadIdx.x & 63;
    const long row = (long)blockIdx.x * 4 + wave;

    const float4* xr = (const float4*)(X + row * 512);
    float4 a = xr[lane * 2];
    float4 b = xr[lane * 2 + 1];

    float s = a.x * a.x + a.y * a.y + a.z * a.z + a.w * a.w
            + b.x * b.x + b.y * b.y + b.z * b.z + b.w * b.w;
#pragma unroll
    for (int off = 32; off; off >>= 1) s += __shfl_xor(s, off, 64);

    const float inv = rsqrtf(s);   // norm ~22.6; eps=1e-8 never binds

    u16x8 o;
    o[0] = f2bf(a.x * inv); o[1] = f2bf(a.y * inv);
    o[2] = f2bf(a.z * inv); o[3] = f2bf(a.w * inv);
    o[4] = f2bf(b.x * inv); o[5] = f2bf(b.y * inv);
    o[6] = f2bf(b.z * inv); o[7] = f2bf(b.w * inv);
    ((u16x8*)(Y + row * 512))[lane] = o;
}

// ------- Kernel 2: C = 1 - Y*Y^T, lower-triangle blocks + mirrored write -------
#define GLDS16(g, l)                                                         \
    __builtin_amdgcn_global_load_lds(                                        \
        (const __attribute__((address_space(1))) void*)(g),                  \
        (__attribute__((address_space(3))) void*)(l), 16, 0, 0)

__global__ __launch_bounds__(256) void cosdist_gemm(
    const unsigned short* __restrict__ Y, float* __restrict__ out) {
    constexpr int N = 8192, K = 512, BM = 128, BK = 32;

    __shared__ __align__(16) short As[BM * BK];
    __shared__ __align__(16) short Bs[BM * BK];

    // triangular decode: block k -> (bi, bj), bi >= bj
    const int k = blockIdx.x;
    int bi = (int)((sqrtf(8.0f * (float)k + 1.0f) - 1.0f) * 0.5f);
    while ((bi + 1) * (bi + 2) / 2 <= k) bi++;
    while (bi * (bi + 1) / 2 > k) bi--;
    const int bj = k - bi * (bi + 1) / 2;
    const int bm = bi * BM;         // row block (>= col block)
    const int bn = bj * BM;
    const bool diag = (bi == bj);

    const int tid  = threadIdx.x;
    const int lane = tid & 63;
    const int wave = tid >> 6;
    const int wr = wave >> 1, wc = wave & 1;

    f32x4 acc[4][4] = {};

    const int c0 = tid, c1 = tid + 256;
    const unsigned short* Ag0 = Y + (size_t)(bm + (c0 >> 2)) * K + ((c0 & 3) << 3);
    const unsigned short* Ag1 = Y + (size_t)(bm + (c1 >> 2)) * K + ((c1 & 3) << 3);
    const unsigned short* Bg0 = Y + (size_t)(bn + (c0 >> 2)) * K + ((c0 & 3) << 3);
    const unsigned short* Bg1 = Y + (size_t)(bn + (c1 >> 2)) * K + ((c1 & 3) << 3);
    short* Al0 = As + c0 * 8;
    short* Al1 = As + c1 * 8;
    short* Bl0 = Bs + c0 * 8;
    short* Bl1 = Bs + c1 * 8;

    const int frow = lane & 15;
    const int fk   = (lane >> 4) << 3;

    for (int k0 = 0; k0 < K; k0 += BK) {
        GLDS16(Ag0 + k0, Al0);
        GLDS16(Ag1 + k0, Al1);
        GLDS16(Bg0 + k0, Bl0);
        GLDS16(Bg1 + k0, Bl1);
        __syncthreads();

        bf16x8 af[4], bfr[4];
#pragma unroll
        for (int t = 0; t < 4; ++t) {
            af[t]  = *(const bf16x8*)&As[(wr * 64 + t * 16 + frow) * BK + fk];
            bfr[t] = *(const bf16x8*)&Bs[(wc * 64 + t * 16 + frow) * BK + fk];
        }
#pragma unroll
        for (int mt = 0; mt < 4; ++mt)
#pragma unroll
            for (int nt = 0; nt < 4; ++nt)
                acc[mt][nt] = __builtin_amdgcn_mfma_f32_16x16x32_bf16(
                    af[mt], bfr[nt], acc[mt][nt], 0, 0, 0);
        __syncthreads();
    }

    // epilogue: direct write + mirrored write (C symmetric); C/D map
    // col=lane&15, row=(lane>>4)*4+reg within each 16x16 sub-tile.
    const int crow0 = wr * 64 + ((lane >> 4) << 2);
    const int ccol0 = wc * 64 + (lane & 15);
#pragma unroll
    for (int mt = 0; mt < 4; ++mt)
#pragma unroll
        for (int nt = 0; nt < 4; ++nt)
#pragma unroll
            for (int r = 0; r < 4; ++r) {
                const int row = bm + crow0 + mt * 16 + r;
                const int col = bn + ccol0 + nt * 16;
                const float v = 1.0f - acc[mt][nt][r];
                out[(size_t)row * N + col] = v;
                if (!diag) out[(size_t)col * N + row] = v;
            }
}

extern "C" void kernel_launch(void* const* d_in, const int* in_sizes, int n_in,
                              void* d_out, int out_size, void* d_ws, size_t ws_size,
                              hipStream_t stream) {
    const float* X = (const float*)d_in[0];          // fp32 [N,512]
    float* out = (float*)d_out;                      // fp32 [N,N]
    unsigned short* Y = (unsigned short*)d_ws;       // bf16 [N,512] scratch

    const int D = 512;
    const int N = in_sizes[0] / D;   // 8192

    normalize_rows<<<N / 4, 256, 0, stream>>>(X, Y);
    const int nb = N / 128;                          // 64
    const int tri = nb * (nb + 1) / 2;               // 2080 blocks
    cosdist_gemm<<<tri, 256, 0, stream>>>(Y, out);
}

// Round 5
// 340.359 us; speedup vs baseline: 1.0761x; 1.0761x over previous
//
#include <hip/hip_runtime.h>

typedef __attribute__((ext_vector_type(8))) short bf16x8;
typedef __attribute__((ext_vector_type(8))) unsigned short u16x8;
typedef __attribute__((ext_vector_type(4))) float f32x4;

__device__ __forceinline__ unsigned short f2bf(float f) {
    unsigned int u = __float_as_uint(f);
    u += 0x7fffu + ((u >> 16) & 1u);   // RNE
    return (unsigned short)(u >> 16);
}

// ---------------- Kernel 1: row-normalize fp32 -> bf16 ----------------
__global__ __launch_bounds__(256) void normalize_rows(
    const float* __restrict__ X, unsigned short* __restrict__ Y) {
    const int wave = threadIdx.x >> 6;
    const int lane = threadIdx.x & 63;
    const long row = (long)blockIdx.x * 4 + wave;

    const float4* xr = (const float4*)(X + row * 512);
    float4 a = xr[lane * 2];
    float4 b = xr[lane * 2 + 1];

    float s = a.x * a.x + a.y * a.y + a.z * a.z + a.w * a.w
            + b.x * b.x + b.y * b.y + b.z * b.z + b.w * b.w;
#pragma unroll
    for (int off = 32; off; off >>= 1) s += __shfl_xor(s, off, 64);

    const float inv = rsqrtf(s);   // norm ~22.6; eps=1e-8 never binds

    u16x8 o;
    o[0] = f2bf(a.x * inv); o[1] = f2bf(a.y * inv);
    o[2] = f2bf(a.z * inv); o[3] = f2bf(a.w * inv);
    o[4] = f2bf(b.x * inv); o[5] = f2bf(b.y * inv);
    o[6] = f2bf(b.z * inv); o[7] = f2bf(b.w * inv);
    ((u16x8*)(Y + row * 512))[lane] = o;
}

// ------- Kernel 2: C = 1 - Y*Y^T, triangular blocks, BK=64, float4 mirror -------
#define GLDS16(g, l)                                                         \
    __builtin_amdgcn_global_load_lds(                                        \
        (const __attribute__((address_space(1))) void*)(g),                  \
        (__attribute__((address_space(3))) void*)(l), 16, 0, 0)

__global__ __launch_bounds__(256) void cosdist_gemm(
    const unsigned short* __restrict__ Y, float* __restrict__ out) {
    constexpr int N = 8192, K = 512, BM = 128, BK = 64;
    // LDS layout per matrix: [h][r][j2] = [2][128][32 shorts]; row stride 64 B
    // (conflict profile identical to the m97 BK=32 layout; glds-contiguous).
    __shared__ __align__(16) short As[BM * BK];   // 8192 shorts = 16 KB
    __shared__ __align__(16) short Bs[BM * BK];

    // triangular decode: block k -> (bi, bj), bi >= bj
    const int kb = blockIdx.x;
    int bi = (int)((sqrtf(8.0f * (float)kb + 1.0f) - 1.0f) * 0.5f);
    while ((bi + 1) * (bi + 2) / 2 <= kb) bi++;
    while (bi * (bi + 1) / 2 > kb) bi--;
    const int bj = kb - bi * (bi + 1) / 2;
    const int bm = bi * BM;
    const int bn = bj * BM;
    const bool diag = (bi == bj);

    const int tid  = threadIdx.x;
    const int lane = tid & 63;
    const int wave = tid >> 6;
    const int wr = wave >> 1, wc = wave & 1;

    f32x4 acc[4][4] = {};

    // staging: 1024 chunks of 16 B per matrix; chunk c -> h=c>>9, r=(c>>2)&127,
    // j2=c&3; global = Y[(bt+r)*K + k0 + h*32 + j2*8]; LDS = buf + c*8 shorts.
    size_t Ao[4], Bo[4];
    int Lo[4];
#pragma unroll
    for (int i = 0; i < 4; ++i) {
        const int c = tid + 256 * i;
        const int h = c >> 9, r = (c >> 2) & 127, j2 = c & 3;
        Ao[i] = (size_t)(bm + r) * K + h * 32 + j2 * 8;
        Bo[i] = (size_t)(bn + r) * K + h * 32 + j2 * 8;
        Lo[i] = c * 8;
    }

    const int frow = lane & 15;
    const int fk   = (lane >> 4) << 3;

    for (int k0 = 0; k0 < K; k0 += BK) {
#pragma unroll
        for (int i = 0; i < 4; ++i) GLDS16(Y + Ao[i] + k0, As + Lo[i]);
#pragma unroll
        for (int i = 0; i < 4; ++i) GLDS16(Y + Bo[i] + k0, Bs + Lo[i]);
        __syncthreads();

#pragma unroll
        for (int s = 0; s < 2; ++s) {
            bf16x8 af[4], bfr[4];
#pragma unroll
            for (int t = 0; t < 4; ++t) {
                af[t]  = *(const bf16x8*)&As[s * 4096 + (wr * 64 + t * 16 + frow) * 32 + fk];
                bfr[t] = *(const bf16x8*)&Bs[s * 4096 + (wc * 64 + t * 16 + frow) * 32 + fk];
            }
#pragma unroll
            for (int mt = 0; mt < 4; ++mt)
#pragma unroll
                for (int nt = 0; nt < 4; ++nt)
                    acc[mt][nt] = __builtin_amdgcn_mfma_f32_16x16x32_bf16(
                        af[mt], bfr[nt], acc[mt][nt], 0, 0, 0);
        }
        __syncthreads();
    }

    // epilogue: C/D map col=lane&15, row=(lane>>4)*4+reg.
    // Lane's 4 values are 4 consecutive ROWS at fixed col -> contiguous in the
    // mirror region: one float4 store. Direct region: 4 scalar stores (each
    // inst still lands 4 rows x 64 B contiguous across the wave).
    const int crow0 = wr * 64 + ((lane >> 4) << 2);
    const int ccol0 = wc * 64 + (lane & 15);
#pragma unroll
    for (int mt = 0; mt < 4; ++mt)
#pragma unroll
        for (int nt = 0; nt < 4; ++nt) {
            const int row0 = bm + crow0 + mt * 16;
            const int col  = bn + ccol0 + nt * 16;
            float4 v;
            v.x = 1.0f - acc[mt][nt][0];
            v.y = 1.0f - acc[mt][nt][1];
            v.z = 1.0f - acc[mt][nt][2];
            v.w = 1.0f - acc[mt][nt][3];
            if (!diag) *(float4*)&out[(size_t)col * N + row0] = v;
            out[(size_t)(row0 + 0) * N + col] = v.x;
            out[(size_t)(row0 + 1) * N + col] = v.y;
            out[(size_t)(row0 + 2) * N + col] = v.z;
            out[(size_t)(row0 + 3) * N + col] = v.w;
        }
}

extern "C" void kernel_launch(void* const* d_in, const int* in_sizes, int n_in,
                              void* d_out, int out_size, void* d_ws, size_t ws_size,
                              hipStream_t stream) {
    const float* X = (const float*)d_in[0];          // fp32 [N,512]
    float* out = (float*)d_out;                      // fp32 [N,N]
    unsigned short* Y = (unsigned short*)d_ws;       // bf16 [N,512] scratch

    const int D = 512;
    const int N = in_sizes[0] / D;   // 8192

    normalize_rows<<<N / 4, 256, 0, stream>>>(X, Y);
    const int nb = N / 128;                          // 64
    const int tri = nb * (nb + 1) / 2;               // 2080 blocks
    cosdist_gemm<<<tri, 256, 0, stream>>>(Y, out);
}